// Round 5
// baseline (143.218 us; speedup 1.0000x reference)
//
#include <hip/hip_runtime.h>
#include <math.h>

// Problem constants
#define NXD 64
#define NYD 48
#define NZD 32
#define NPT (NXD*NYD*NZD)   // 98304 points
#define PN  10              // neighbors per point
#define MF  5               // fourier modes
#define H1  64
#define H2  32
#define H3  8

// Block geometry: 256 threads = 4 waves; 32 points = 320 rows per block;
// each wave owns 8 points = 80 rows = 5 tiles of 16 rows.
#define PTS_PER_BLOCK 32
#define ROWS_PER_BLOCK (PTS_PER_BLOCK*PN)   // 320
#define TILES_PER_WAVE 5

// LDS row strides (bf16 elems) — multiples of 8 so rows are 16B-aligned for b128
#define A1S 40   // 16 rows x 40 (33 ch + pad)
#define A2S 72   // 16 rows x 72 (64 ch + pad)
#define A3S 40   // 16 rows x 40 (32 ch + pad)

typedef __attribute__((ext_vector_type(8))) short short8;  // 8 bf16 = 4 VGPRs
typedef __attribute__((ext_vector_type(4))) float f32x4;

extern "C" __device__ float __ocml_exp2_f32(float);

// exact RNE fp32->bf16 (one-time weight conversion only)
__device__ __forceinline__ short f2bf(float f) {
    unsigned u = __float_as_uint(f);
    unsigned r = (u + 0x7fffu + ((u >> 16) & 1u)) >> 16;
    return (short)r;
}
// fast fp32->bf16 (round-half-up): 2 VALU
__device__ __forceinline__ unsigned short f2bf_hu(float f) {
    return (unsigned short)((__float_as_uint(f) + 0x8000u) >> 16);
}

// gelu = x * sigmoid(1.5957691*x + 0.07135482*x^3)  [tanh-form, sigma rewrite]
// = x * rcp(1 + e^{-t}); fold sign into poly; ~3e-4 abs error vs exact erf-gelu
__device__ __forceinline__ float gelu_fast(float x) {
    float x2 = x * x;
    float p  = __builtin_fmaf(-0.07135482f, x2, -1.59576912f); // p = -(t/x)
    float s  = x * p;                                          // s = -t
    float E  = __ocml_exp2_f32(s * 1.44269504f);               // e^{-t}
    return x * __builtin_amdgcn_rcpf(E + 1.0f);
}
// tanh(v) = 2*sigmoid(2v) - 1; saturates correctly at +/-inf
__device__ __forceinline__ float tanh_fast(float v) {
    float E = __ocml_exp2_f32(v * -2.88539008f);               // e^{-2v}
    float r = __builtin_amdgcn_rcpf(E + 1.0f);
    return __builtin_fmaf(2.0f, r, -1.0f);
}
// sin/cos of (r revolutions): explicit fract for guaranteed hw-valid domain
__device__ __forceinline__ void sincos_rev(float r, float* s, float* c) {
    float f = __builtin_amdgcn_fractf(r);
    *s = __builtin_amdgcn_sinf(f);
    *c = __builtin_amdgcn_cosf(f);
}

__global__ __launch_bounds__(256) void domino_mfma_kernel(
    const float* __restrict__ x,      // (NPT*PN, 3)
    const float* __restrict__ freqs,  // (MF,)
    const float* __restrict__ W1,     // (33, 64)
    const float* __restrict__ b1,
    const float* __restrict__ W2,     // (64, 32)
    const float* __restrict__ b2,
    const float* __restrict__ W3,     // (32, 8)
    const float* __restrict__ b3,
    float* __restrict__ out)          // (8, NPT)
{
    __shared__ float obuf[ROWS_PER_BLOCK * 9];                  // masked tanh rows
    __shared__ __align__(16) unsigned short a1buf[4][16 * A1S]; // features, A-layout
    __shared__ __align__(16) unsigned short a2buf[4][16 * A2S]; // L1->L2 transpose
    __shared__ __align__(16) unsigned short a3buf[4][16 * A3S]; // L2->L3 transpose
    __shared__ __align__(16) float mcx[4][16];   // x-coordinate per row (mask)
    __shared__ __align__(16) float mv32[4][16];  // feature ch32 = cos(f4*z) per row

    const int tid  = threadIdx.x;
    const int w    = tid >> 6;      // wave id 0..3
    const int lane = tid & 63;
    const int lr   = lane & 15;     // A-row / B-col / C-col index; also trig feature idx
    const int lg   = lane >> 4;     // k-group / C-row-group; also trig row group

    // ---- loop-invariant task params
    // trig task: feature idx = lr (m = lr/3, d = lr%3), rows lg+4i
    const int sc_m = (lr < 15) ? (lr / 3) : 4;
    const int sc_d = lr % 3;
    const float scale_rev = freqs[sc_m] * 0.15915494309189535f; // freq/(2*pi)
    // coord staging task (lanes 0..47): row = lane/3, dim = lane%3
    const int st_row = lane / 3;
    const int st_d   = lane % 3;

    // ---- preload weight fragments (once per wave)
    // B layout for 16x16x32: n = lane&15, k = (lane>>4)*8 + j
    short8 B1f[4];                      // layer1: K=32 (ch0..31), N=64 -> 4 n-tiles
    float  w32[4], bv1[4];              // ch32 rank-1 fixup weights + bias
    #pragma unroll
    for (int t1 = 0; t1 < 4; ++t1) {
        #pragma unroll
        for (int j = 0; j < 8; ++j)
            B1f[t1][j] = f2bf(W1[(lg*8 + j)*H1 + t1*16 + lr]);
        w32[t1] = W1[32*H1 + t1*16 + lr];
        bv1[t1] = b1[t1*16 + lr];
    }
    short8 B2f[2][2];                   // layer2: K=64 (2 steps), N=32 -> 2 n-tiles
    float  bv2[2];
    #pragma unroll
    for (int s = 0; s < 2; ++s)
        #pragma unroll
        for (int t2 = 0; t2 < 2; ++t2)
            #pragma unroll
            for (int j = 0; j < 8; ++j)
                B2f[s][t2][j] = f2bf(W2[(s*32 + lg*8 + j)*H2 + t2*16 + lr]);
    #pragma unroll
    for (int t2 = 0; t2 < 2; ++t2) bv2[t2] = b2[t2*16 + lr];

    short8 B3f;                         // layer3: K=32, N=16 (cols 8..15 zero)
    float  bv3 = (lr < H3) ? b3[lr] : 0.0f;
    #pragma unroll
    for (int j = 0; j < 8; ++j)
        B3f[j] = (lr < H3) ? f2bf(W3[(lg*8 + j)*H3 + lr]) : (short)0;

    const int wrow0 = blockIdx.x * ROWS_PER_BLOCK + w * (TILES_PER_WAVE*16);

    #pragma unroll 1
    for (int t = 0; t < TILES_PER_WAVE; ++t) {
        const int row0 = wrow0 + t*16;   // global row base of this 16-row tile

        // ---- (a) coord staging: lanes 0..47 each place one coord (row, dim)
        if (lane < 48) {
            const float c = x[(size_t)(row0 + st_row)*3 + st_d];
            a1buf[w][st_row*A1S + st_d] = f2bf_hu(c);
            if (st_d == 0) mcx[w][st_row] = c;
        }
        // ---- (b) distributed trig: lane handles feature idx lr for 4 rows
        if (lr < 15) {
            #pragma unroll
            for (int i = 0; i < 4; ++i) {
                const int rr = lg + 4*i;
                const float c = x[(size_t)(row0 + rr)*3 + sc_d];
                float s, co;
                sincos_rev(scale_rev * c, &s, &co);
                a1buf[w][rr*A1S + 3  + lr] = f2bf_hu(s);
                a1buf[w][rr*A1S + 18 + lr] = f2bf_hu(co);
                if (lr == 14) mv32[w][rr] = co;   // ch32 = cos(f4*z)
            }
        }
        // same-wave LDS write->read: in-order, compiler inserts lgkmcnt (no barrier)

        // ---- (c) A1 fragment: one ds_read_b128 (row lr, ch lg*8..lg*8+7)
        const short8 a1 = *(const short8*)&a1buf[w][lr*A1S + lg*8];

        // ---- Layer 1: 4 n-tiles, K=32, bias-initialized accumulators
        f32x4 c1[4];
        #pragma unroll
        for (int t1 = 0; t1 < 4; ++t1) {
            f32x4 ci = {bv1[t1], bv1[t1], bv1[t1], bv1[t1]};
            c1[t1] = __builtin_amdgcn_mfma_f32_16x16x32_bf16(a1, B1f[t1], ci, 0, 0, 0);
        }
        // ch32 rank-1 fixup + mask coords for this lane's 4 C-rows
        const f32x4 v32r = *(const f32x4*)&mv32[w][lg*4];
        const f32x4 mxr  = *(const f32x4*)&mcx[w][lg*4];
        #pragma unroll
        for (int t1 = 0; t1 < 4; ++t1)
            #pragma unroll
            for (int r = 0; r < 4; ++r)
                c1[t1][r] = __builtin_fmaf(v32r[r], w32[t1], c1[t1][r]);
        #pragma unroll
        for (int t1 = 0; t1 < 4; ++t1)
            #pragma unroll
            for (int r = 0; r < 4; ++r)
                c1[t1][r] = gelu_fast(c1[t1][r]);

        // ---- transpose L1 out (C-layout) -> A-layout via LDS
        #pragma unroll
        for (int t1 = 0; t1 < 4; ++t1)
            #pragma unroll
            for (int r = 0; r < 4; ++r)
                a2buf[w][(lg*4 + r)*A2S + t1*16 + lr] = f2bf_hu(c1[t1][r]);
        short8 a2f[2];
        #pragma unroll
        for (int s = 0; s < 2; ++s)
            a2f[s] = *(const short8*)&a2buf[w][lr*A2S + s*32 + lg*8];

        // ---- Layer 2: K=64 (2 steps), 2 n-tiles
        f32x4 c2[2];
        #pragma unroll
        for (int t2 = 0; t2 < 2; ++t2) {
            f32x4 ci = {bv2[t2], bv2[t2], bv2[t2], bv2[t2]};
            ci = __builtin_amdgcn_mfma_f32_16x16x32_bf16(a2f[0], B2f[0][t2], ci, 0, 0, 0);
            c2[t2] = __builtin_amdgcn_mfma_f32_16x16x32_bf16(a2f[1], B2f[1][t2], ci, 0, 0, 0);
        }
        #pragma unroll
        for (int t2 = 0; t2 < 2; ++t2)
            #pragma unroll
            for (int r = 0; r < 4; ++r)
                c2[t2][r] = gelu_fast(c2[t2][r]);

        // ---- transpose L2 out -> A-layout
        #pragma unroll
        for (int t2 = 0; t2 < 2; ++t2)
            #pragma unroll
            for (int r = 0; r < 4; ++r)
                a3buf[w][(lg*4 + r)*A3S + t2*16 + lr] = f2bf_hu(c2[t2][r]);
        const short8 a3f = *(const short8*)&a3buf[w][lr*A3S + lg*8];

        // ---- Layer 3: K=32, N=16 (8 valid)
        f32x4 c3 = {bv3, bv3, bv3, bv3};
        c3 = __builtin_amdgcn_mfma_f32_16x16x32_bf16(a3f, B3f, c3, 0, 0, 0);

        // ---- tanh, mask, store per-row result to block buffer
        #pragma unroll
        for (int r = 0; r < 4; ++r) {
            const int brow = w*(TILES_PER_WAVE*16) + t*16 + lg*4 + r;
            const float mk = (fabsf(mxr[r]) > 1e-6f) ? 1.0f : 0.0f;
            if (lr < H3) obuf[brow*9 + lr] = mk * tanh_fast(c3[r]);
        }
    }

    __syncthreads();

    // ---- neighbor reduction: 32 points x 8 channels; coalesced final store
    {
        const int p  = tid & 31;   // point-in-block: consecutive lanes -> consecutive out
        const int ch = tid >> 5;   // 0..7
        float sum = 0.0f;
        #pragma unroll
        for (int i = 0; i < PN; ++i) sum += obuf[(p*PN + i)*9 + ch];
        const int gp = blockIdx.x * PTS_PER_BLOCK + p;
        out[(size_t)ch * NPT + gp] = sum;
    }
}

extern "C" void kernel_launch(void* const* d_in, const int* in_sizes, int n_in,
                              void* d_out, int out_size, void* d_ws, size_t ws_size,
                              hipStream_t stream) {
    // setup_inputs order: x, grid(unused), freqs, W1, b1, W2, b2, W3, b3
    const float* x     = (const float*)d_in[0];
    const float* freqs = (const float*)d_in[2];
    const float* W1    = (const float*)d_in[3];
    const float* b1    = (const float*)d_in[4];
    const float* W2    = (const float*)d_in[5];
    const float* b2    = (const float*)d_in[6];
    const float* W3    = (const float*)d_in[7];
    const float* b3    = (const float*)d_in[8];
    float* out = (float*)d_out;

    const int grid = NPT / PTS_PER_BLOCK;   // 3072 blocks, no remainder
    domino_mfma_kernel<<<grid, 256, 0, stream>>>(x, freqs, W1, b1, W2, b2, W3, b3, out);
}

// Round 6
// 140.362 us; speedup vs baseline: 1.0203x; 1.0203x over previous
//
#include <hip/hip_runtime.h>
#include <math.h>

// Problem constants
#define NXD 64
#define NYD 48
#define NZD 32
#define NPT (NXD*NYD*NZD)   // 98304 points
#define PN  10              // neighbors per point
#define MF  5               // fourier modes
#define H1  64
#define H2  32
#define H3  8

// Block geometry: 256 threads = 4 waves; 32 points = 320 rows per block;
// each wave owns 8 points = 80 rows = 5 tiles of 16 rows.
#define PTS_PER_BLOCK 32
#define ROWS_PER_BLOCK (PTS_PER_BLOCK*PN)   // 320
#define TILES_PER_WAVE 5

// LDS row strides (bf16 elems) — multiples of 8 so rows are 16B-aligned for b128
#define A2S 72   // 16 rows x 72 (64 ch + pad)
#define A3S 40   // 16 rows x 40 (32 ch + pad) — aliased into a2buf space

typedef __attribute__((ext_vector_type(8))) short short8;  // 8 bf16 = 4 VGPRs
typedef __attribute__((ext_vector_type(4))) float f32x4;

extern "C" __device__ float __ocml_exp2_f32(float);

// exact RNE fp32->bf16 (one-time weight conversion only)
__device__ __forceinline__ short f2bf(float f) {
    unsigned u = __float_as_uint(f);
    unsigned r = (u + 0x7fffu + ((u >> 16) & 1u)) >> 16;
    return (short)r;
}
// fast fp32->bf16 (round-half-up): 2 VALU
__device__ __forceinline__ unsigned short f2bf_hu(float f) {
    return (unsigned short)((__float_as_uint(f) + 0x8000u) >> 16);
}
// pack two fp32 -> one dword of 2 bf16 (lo in low half): 2 adds + v_perm
__device__ __forceinline__ unsigned pack2_bf16(float lo, float hi) {
    return __builtin_amdgcn_perm(__float_as_uint(hi) + 0x8000u,
                                 __float_as_uint(lo) + 0x8000u, 0x07060302u);
}

// gelu = x * sigmoid(1.5957691 x + 0.07135482 x^3), log2e pre-folded:
// gelu = x * rcp(1 + exp2(x * (-2.3022086 - 0.10294296 x^2)))
// ~3e-4 abs error vs exact erf-gelu; saturates correctly at +/-inf
__device__ __forceinline__ float gelu_fast(float x) {
    float x2 = x * x;
    float p  = __builtin_fmaf(-0.10294296f, x2, -2.30220846f);
    float E  = __ocml_exp2_f32(x * p);
    return x * __builtin_amdgcn_rcpf(E + 1.0f);
}
// tanh(v) = 2*sigmoid(2v) - 1; saturates correctly at +/-inf
__device__ __forceinline__ float tanh_fast(float v) {
    float E = __ocml_exp2_f32(v * -2.88539008f);
    float r = __builtin_amdgcn_rcpf(E + 1.0f);
    return __builtin_fmaf(2.0f, r, -1.0f);
}

__global__ __launch_bounds__(256) void domino_mfma_kernel(
    const float* __restrict__ x,      // (NPT*PN, 3)
    const float* __restrict__ freqs,  // (MF,)
    const float* __restrict__ W1,     // (33, 64)
    const float* __restrict__ b1,
    const float* __restrict__ W2,     // (64, 32)
    const float* __restrict__ b2,
    const float* __restrict__ W3,     // (32, 8)
    const float* __restrict__ b3,
    float* __restrict__ out)          // (8, NPT)
{
    __shared__ float obuf[ROWS_PER_BLOCK * 9];                  // masked tanh rows
    __shared__ __align__(16) unsigned short a2buf[4][16 * A2S]; // L1->L2 transpose; a3 aliased inside
    __shared__ __align__(16) float mcx[4][16];   // x-coordinate per row (mask)
    __shared__ __align__(16) float mv32[4][16];  // feature ch32 = cos(f4*z) per row

    const int tid  = threadIdx.x;
    const int w    = tid >> 6;      // wave id 0..3
    const int lane = tid & 63;
    const int lr   = lane & 15;     // A-row / B-col / C-col index
    const int lg   = lane >> 4;     // k-group / C-row-group

    // ---- per-lane channel metadata (loop-invariant): channel k = lg*8+j
    // feat layout: [x,y,z (0..2), sin(scaled) (3..17), cos(scaled) (18..32)]
    // scaled idx = m*3+d; cos(2*pi*t) = sin(2*pi*(t+0.25))
    float frv[MF];
    #pragma unroll
    for (int m = 0; m < MF; ++m) frv[m] = freqs[m] * 0.15915494309189535f; // rev scale
    float sc[8], ph[8];
    int   djv[8];
    bool  rawv[8];
    {
        const int k0 = lg * 8;
        #pragma unroll
        for (int j = 0; j < 8; ++j) {
            const int  kk    = k0 + j;
            const bool raw   = (kk < 3);
            const bool isCos = (kk >= 18);
            int idx = isCos ? (kk - 18) : (kk - 3);
            if (raw) idx = 0;
            const int m = idx / 3;
            const int d = idx - m * 3;
            float f = (m == 0) ? frv[0] : (m == 1) ? frv[1] : (m == 2) ? frv[2]
                      : (m == 3) ? frv[3] : frv[4];
            sc[j]   = raw ? 0.0f : f;
            ph[j]   = isCos ? 0.25f : 0.0f;
            djv[j]  = raw ? kk : d;
            rawv[j] = raw;
        }
    }

    // ---- preload weight fragments (once per wave)
    // B layout for 16x16x32: n = lane&15, k = (lane>>4)*8 + j
    short8 B1f[4];                      // layer1: K=32 (ch0..31), N=64 -> 4 n-tiles
    float  w32[4], bv1[4];              // ch32 rank-1 fixup weights + bias
    #pragma unroll
    for (int t1 = 0; t1 < 4; ++t1) {
        #pragma unroll
        for (int j = 0; j < 8; ++j)
            B1f[t1][j] = f2bf(W1[(lg*8 + j)*H1 + t1*16 + lr]);
        w32[t1] = W1[32*H1 + t1*16 + lr];
        bv1[t1] = b1[t1*16 + lr];
    }
    short8 B2f[2][2];                   // layer2: K=64 (2 steps), N=32 -> 2 n-tiles
    float  bv2[2];
    #pragma unroll
    for (int s = 0; s < 2; ++s)
        #pragma unroll
        for (int t2 = 0; t2 < 2; ++t2)
            #pragma unroll
            for (int j = 0; j < 8; ++j)
                B2f[s][t2][j] = f2bf(W2[(s*32 + lg*8 + j)*H2 + t2*16 + lr]);
    #pragma unroll
    for (int t2 = 0; t2 < 2; ++t2) bv2[t2] = b2[t2*16 + lr];

    short8 B3f;                         // layer3: K=32, N=16 (cols 8..15 zero)
    float  bv3 = (lr < H3) ? b3[lr] : 0.0f;
    #pragma unroll
    for (int j = 0; j < 8; ++j)
        B3f[j] = (lr < H3) ? f2bf(W3[(lg*8 + j)*H3 + lr]) : (short)0;

    const int wrow0 = blockIdx.x * ROWS_PER_BLOCK + w * (TILES_PER_WAVE*16);

    #pragma unroll 1
    for (int t = 0; t < TILES_PER_WAVE; ++t) {
        const int myrow = wrow0 + t*16 + lr;  // the A-row this lane generates

        // ---- load coords (4 lane-groups read the same 12B; L1 broadcast)
        const float* xp = x + (size_t)myrow * 3;
        const float cx = xp[0], cy = xp[1], cz = xp[2];

        // stage per-row mask coord and feature ch32 = cos(f4*z)
        if (lg == 0) {
            mcx[w][lr] = cx;
            float f = __builtin_amdgcn_fractf(__builtin_fmaf(frv[4], cz, 0.25f));
            mv32[w][lr] = __builtin_amdgcn_sinf(f);
        }

        // ---- branchless per-lane features: exactly the 8 channels this lane owns
        float fv[8];
        #pragma unroll
        for (int j = 0; j < 8; ++j) {
            const float c = (djv[j] == 0) ? cx : ((djv[j] == 1) ? cy : cz);
            const float f = __builtin_amdgcn_fractf(__builtin_fmaf(sc[j], c, ph[j]));
            const float v = __builtin_amdgcn_sinf(f);
            fv[j] = rawv[j] ? c : v;
        }
        union { unsigned u[4]; short8 s8; } a1u;
        #pragma unroll
        for (int j = 0; j < 4; ++j) a1u.u[j] = pack2_bf16(fv[2*j], fv[2*j+1]);
        const short8 a1 = a1u.s8;

        // ---- Layer 1: 4 n-tiles, K=32, bias-initialized accumulators
        f32x4 c1[4];
        #pragma unroll
        for (int t1 = 0; t1 < 4; ++t1) {
            f32x4 ci = {bv1[t1], bv1[t1], bv1[t1], bv1[t1]};
            c1[t1] = __builtin_amdgcn_mfma_f32_16x16x32_bf16(a1, B1f[t1], ci, 0, 0, 0);
        }
        // ch32 rank-1 fixup + mask coords for this lane's 4 C-rows (float4 LDS reads)
        const f32x4 v32r = *(const f32x4*)&mv32[w][lg*4];
        const f32x4 mxr  = *(const f32x4*)&mcx[w][lg*4];
        #pragma unroll
        for (int t1 = 0; t1 < 4; ++t1)
            #pragma unroll
            for (int r = 0; r < 4; ++r)
                c1[t1][r] = __builtin_fmaf(v32r[r], w32[t1], c1[t1][r]);
        #pragma unroll
        for (int t1 = 0; t1 < 4; ++t1)
            #pragma unroll
            for (int r = 0; r < 4; ++r)
                c1[t1][r] = gelu_fast(c1[t1][r]);

        // ---- transpose L1 out (C-layout) -> A-layout via LDS
        #pragma unroll
        for (int t1 = 0; t1 < 4; ++t1)
            #pragma unroll
            for (int r = 0; r < 4; ++r)
                a2buf[w][(lg*4 + r)*A2S + t1*16 + lr] = f2bf_hu(c1[t1][r]);
        short8 a2f[2];
        #pragma unroll
        for (int s = 0; s < 2; ++s)
            a2f[s] = *(const short8*)&a2buf[w][lr*A2S + s*32 + lg*8];

        // ---- Layer 2: K=64 (2 steps), 2 n-tiles
        f32x4 c2[2];
        #pragma unroll
        for (int t2 = 0; t2 < 2; ++t2) {
            f32x4 ci = {bv2[t2], bv2[t2], bv2[t2], bv2[t2]};
            ci = __builtin_amdgcn_mfma_f32_16x16x32_bf16(a2f[0], B2f[0][t2], ci, 0, 0, 0);
            c2[t2] = __builtin_amdgcn_mfma_f32_16x16x32_bf16(a2f[1], B2f[1][t2], ci, 0, 0, 0);
        }
        #pragma unroll
        for (int t2 = 0; t2 < 2; ++t2)
            #pragma unroll
            for (int r = 0; r < 4; ++r)
                c2[t2][r] = gelu_fast(c2[t2][r]);

        // ---- transpose L2 out -> A-layout, aliased into a2buf space.
        // Safe: a2f reads are forced complete (data dep through MFMA/gelu) before
        // these writes issue, and same-wave DS ops process in order.
        unsigned short* a3p = &a2buf[w][0];
        #pragma unroll
        for (int t2 = 0; t2 < 2; ++t2)
            #pragma unroll
            for (int r = 0; r < 4; ++r)
                a3p[(lg*4 + r)*A3S + t2*16 + lr] = f2bf_hu(c2[t2][r]);
        const short8 a3f = *(const short8*)&a3p[lr*A3S + lg*8];

        // ---- Layer 3: K=32, N=16 (8 valid)
        f32x4 c3 = {bv3, bv3, bv3, bv3};
        c3 = __builtin_amdgcn_mfma_f32_16x16x32_bf16(a3f, B3f, c3, 0, 0, 0);

        // ---- tanh, mask, store per-row result to block buffer
        #pragma unroll
        for (int r = 0; r < 4; ++r) {
            const int brow = w*(TILES_PER_WAVE*16) + t*16 + lg*4 + r;
            const float mk = (fabsf(mxr[r]) > 1e-6f) ? 1.0f : 0.0f;
            if (lr < H3) obuf[brow*9 + lr] = mk * tanh_fast(c3[r]);
        }
    }

    __syncthreads();

    // ---- neighbor reduction: 32 points x 8 channels; coalesced final store
    {
        const int p  = tid & 31;   // consecutive lanes -> consecutive out addresses
        const int ch = tid >> 5;   // 0..7
        float sum = 0.0f;
        #pragma unroll
        for (int i = 0; i < PN; ++i) sum += obuf[(p*PN + i)*9 + ch];
        const int gp = blockIdx.x * PTS_PER_BLOCK + p;
        out[(size_t)ch * NPT + gp] = sum;
    }
}

extern "C" void kernel_launch(void* const* d_in, const int* in_sizes, int n_in,
                              void* d_out, int out_size, void* d_ws, size_t ws_size,
                              hipStream_t stream) {
    // setup_inputs order: x, grid(unused), freqs, W1, b1, W2, b2, W3, b3
    const float* x     = (const float*)d_in[0];
    const float* freqs = (const float*)d_in[2];
    const float* W1    = (const float*)d_in[3];
    const float* b1    = (const float*)d_in[4];
    const float* W2    = (const float*)d_in[5];
    const float* b2    = (const float*)d_in[6];
    const float* W3    = (const float*)d_in[7];
    const float* b3    = (const float*)d_in[8];
    float* out = (float*)d_out;

    const int grid = NPT / PTS_PER_BLOCK;   // 3072 blocks, no remainder
    domino_mfma_kernel<<<grid, 256, 0, stream>>>(x, freqs, W1, b1, W2, b2, W3, b3, out);
}